// Round 9
// baseline (17.964 us; speedup 1.0000x reference)
//
#include <hip/hip_runtime.h>
#include <hip/hip_bf16.h>

#define EPS_F 1e-8f
#define MIN_THRESH_F 0.1f

// Two kernels. In-kernel cross-block completion ruled out on MI355X:
// R4 grid.sync = 141us, R6 threadfence+atomic last-block = 82us, R1
// same-address atomic burst = +48us.
// Gather: one row per HALF-wave (32 lanes x 4 float4 = 512 floats = D).
// 512 blocks x 1024 threads = 8192 waves, 2 blocks/CU = 100% occupancy.
// Finalize: ONE 64-lane wave, 4 float4/lane, no LDS, no syncthreads.
// d_ws: float2 partials[512], written unconditionally -> deterministic,
// no memset, no atomics.

__global__ __launch_bounds__(1024) void cosloss_main(
    const float* __restrict__ a, const float* __restrict__ b,
    const int* __restrict__ labels, int N, float2* __restrict__ partials)
{
    const int lane = threadIdx.x & 63;
    const int wave = threadIdx.x >> 6;      // 0..15
    const int sub  = lane & 31;             // lane within half-wave
    const int half = lane >> 5;             // 0 or 1
    const int hwid = (blockIdx.x << 5) + (wave << 1) + half;  // half-wave id
    const int nhw  = gridDim.x << 5;        // 16384 half-waves

    float total = 0.0f, cnt = 0.0f;

    for (int r = hwid; r < N; r += nhw) {   // trip count 1 for N=16384
        const int label = labels[r];
        const char* pa = (const char*)a + ((long long)label << 11) + (sub << 4);
        const char* pb = (const char*)b + ((long long)label << 11) + (sub << 4);

        float4 A0 = *(const float4*)(pa);
        float4 A1 = *(const float4*)(pa + 512);
        float4 A2 = *(const float4*)(pa + 1024);
        float4 A3 = *(const float4*)(pa + 1536);
        float4 B0 = *(const float4*)(pb);
        float4 B1 = *(const float4*)(pb + 512);
        float4 B2 = *(const float4*)(pb + 1024);
        float4 B3 = *(const float4*)(pb + 1536);

        // keep all 8 loads in flight before any FMA (distinct dest regs)
        asm volatile("" ::
            "v"(A0.x), "v"(A0.w), "v"(A1.x), "v"(A1.w),
            "v"(A2.x), "v"(A2.w), "v"(A3.x), "v"(A3.w),
            "v"(B0.x), "v"(B0.w), "v"(B1.x), "v"(B1.w),
            "v"(B2.x), "v"(B2.w), "v"(B3.x), "v"(B3.w));

        float ip = A0.x*B0.x + A0.y*B0.y + A0.z*B0.z + A0.w*B0.w
                 + A1.x*B1.x + A1.y*B1.y + A1.z*B1.z + A1.w*B1.w
                 + A2.x*B2.x + A2.y*B2.y + A2.z*B2.z + A2.w*B2.w
                 + A3.x*B3.x + A3.y*B3.y + A3.z*B3.z + A3.w*B3.w;
        float s1 = A0.x*A0.x + A0.y*A0.y + A0.z*A0.z + A0.w*A0.w
                 + A1.x*A1.x + A1.y*A1.y + A1.z*A1.z + A1.w*A1.w
                 + A2.x*A2.x + A2.y*A2.y + A2.z*A2.z + A2.w*A2.w
                 + A3.x*A3.x + A3.y*A3.y + A3.z*A3.z + A3.w*A3.w;
        float s2 = B0.x*B0.x + B0.y*B0.y + B0.z*B0.z + B0.w*B0.w
                 + B1.x*B1.x + B1.y*B1.y + B1.z*B1.z + B1.w*B1.w
                 + B2.x*B2.x + B2.y*B2.y + B2.z*B2.z + B2.w*B2.w
                 + B3.x*B3.x + B3.y*B3.y + B3.z*B3.z + B3.w*B3.w;

        // 5-step butterfly within the 32-lane half
        #pragma unroll
        for (int off = 16; off >= 1; off >>= 1) {
            ip += __shfl_xor(ip, off);
            s1 += __shfl_xor(s1, off);
            s2 += __shfl_xor(s2, off);
        }

        if (sub == 0) {
            float c = ip / fmaxf(sqrtf(s1) * sqrtf(s2), EPS_F);
            if (c >= MIN_THRESH_F) { total += c; cnt += 1.0f; }
        }
    }

    // 32 half-wave partials -> parallel 32-lane shuffle reduce (no serial loop)
    __shared__ float st[32], sc[32];
    if (sub == 0) { st[(wave << 1) + half] = total; sc[(wave << 1) + half] = cnt; }
    __syncthreads();
    if (threadIdx.x < 32) {
        float t = st[threadIdx.x], c = sc[threadIdx.x];
        #pragma unroll
        for (int off = 16; off >= 1; off >>= 1) {
            t += __shfl_xor(t, off);
            c += __shfl_xor(c, off);
        }
        if (threadIdx.x == 0) partials[blockIdx.x] = make_float2(t, c);
    }
}

__global__ __launch_bounds__(64) void cosloss_final(
    const float4* __restrict__ partials4, float* __restrict__ out)
{
    // 512 float2 partials = 256 float4; one wave, 4 float4 per lane.
    const int lane = threadIdx.x;
    float t = 0.0f, c = 0.0f;
    #pragma unroll
    for (int k = 0; k < 4; ++k) {
        float4 p = partials4[lane + (k << 6)];
        t += p.x + p.z;
        c += p.y + p.w;
    }
    #pragma unroll
    for (int off = 32; off >= 1; off >>= 1) {
        t += __shfl_xor(t, off);
        c += __shfl_xor(c, off);
    }
    if (lane == 0) {
        if (c < 1.0f) c = 1.0f;
        out[0] = t / c;
    }
}

extern "C" void kernel_launch(void* const* d_in, const int* in_sizes, int n_in,
                              void* d_out, int out_size, void* d_ws, size_t ws_size,
                              hipStream_t stream)
{
    const float* a      = (const float*)d_in[0];
    const float* b      = (const float*)d_in[1];
    const int*   labels = (const int*)d_in[2];
    const int N = in_sizes[2];

    float2* partials = (float2*)d_ws;

    cosloss_main<<<512, 1024, 0, stream>>>(a, b, labels, N, partials);
    cosloss_final<<<1, 64, 0, stream>>>((const float4*)partials, (float*)d_out);
}